// Round 10
// baseline (426.267 us; speedup 1.0000x reference)
//
#include <hip/hip_runtime.h>
#include <hip/hip_bf16.h>
#include <math.h>

#define N 4096
#define IN_FT 512
#define OUT_FT 512
#define COS_THR 0.5f
#define COS_K 10
#define EPSN 1e-12f
#define CAP 256          // max stored nnz per row/col (actual ~10)
#define NW (N / 32)      // bitmask words per row

#define CB 128           // cos tile
#define CK 32            // cos k-step
#define CNB (N / CB)     // 32 cos block-rows

typedef short s16x8 __attribute__((ext_vector_type(8)));
typedef float f32x4 __attribute__((ext_vector_type(4)));

__device__ __forceinline__ unsigned short f2bf(float f) {
    unsigned u = __float_as_uint(f);
    u += 0x7fff + ((u >> 16) & 1);          // RNE to bf16
    return (unsigned short)(u >> 16);
}
__device__ __forceinline__ float bf2f(unsigned short h) {
    return __uint_as_float(((unsigned)h) << 16);
}

// ---------- row-normalize x ----------
__global__ __launch_bounds__(256) void rownorm_k(const float* __restrict__ x,
                                                 float* __restrict__ xn) {
    int row = blockIdx.x;
    const float* xr = x + (size_t)row * IN_FT;
    float s = 0.f;
    for (int j = threadIdx.x; j < IN_FT; j += 256) { float v = xr[j]; s += v * v; }
    __shared__ float red[256];
    red[threadIdx.x] = s; __syncthreads();
    for (int off = 128; off > 0; off >>= 1) {
        if (threadIdx.x < off) red[threadIdx.x] += red[threadIdx.x + off];
        __syncthreads();
    }
    float inv = 1.0f / fmaxf(sqrtf(red[0]), 1e-12f);
    for (int j = threadIdx.x; j < IN_FT; j += 256)
        xn[(size_t)row * IN_FT + j] = xr[j] * inv;
}

// ---------- symmetric cos GEMM: upper-tri 128-blocks, mirror fused ----------
// 128 threads, 16x8 thread-tile: 128 FMA per 96 B LDS reads (1.33 FMA/B) so
// VALU, not LDS bandwidth, is the binding pipe. Bs keeps the round-9 chunk
// permutation (conflict-free b128 reads); As identity (2-way broadcast, free).
// Per-element chain = strict ascending k, one FMA per k -> cos BIT-IDENTICAL
// to all prior rounds; mirror uses IEEE a*b==b*a.
__global__ __launch_bounds__(128) void cos_sym_k(const float* __restrict__ A,
                                                 float* __restrict__ C) {
    __shared__ __align__(16) float As[CK][CB + 4];
    __shared__ __align__(16) float Bs[CK][CB + 4];
    int t = blockIdx.x;                       // 0 .. 527
    int by = 0;
    while (t >= CNB - by) { t -= CNB - by; ++by; }
    int bx = by + t;                          // by <= bx
    int i0 = by * CB, j0 = bx * CB;
    int tid = threadIdx.x;                    // 0..127
    int tx = tid & 15;                        // B cols: tx*8 .. tx*8+7
    int ty = tid >> 4;                        // A rows: ty*16 .. ty*16+15 (0..7)
    int sm = tid >> 1;                        // staging row 0..63 (+64 second half)
    int sk = (tid & 1) * 16;                  // staging k offset 0/16
    // permuted physical column for Bs staging writes of logical col c:
    // chunk perm p(ch) = (ch>>1) | ((ch&1)<<4)
    int sch0 = sm >> 2;
    int pb0 = (((sch0 >> 1) | ((sch0 & 1) << 4)) << 2) | (sm & 3);
    int sch1 = (sm + 64) >> 2;
    int pb1 = (((sch1 >> 1) | ((sch1 & 1) << 4)) << 2) | (sm & 3);
    float acc[16][8] = {{0.f}};
    for (int k0 = 0; k0 < IN_FT; k0 += CK) {
        // stage 128 rows x 32 k for A and B: each thread 2 rows x 16 k each
        float4 a0 = *(const float4*)&A[(size_t)(i0 + sm) * IN_FT + k0 + sk + 0];
        float4 a1 = *(const float4*)&A[(size_t)(i0 + sm) * IN_FT + k0 + sk + 4];
        float4 a2 = *(const float4*)&A[(size_t)(i0 + sm) * IN_FT + k0 + sk + 8];
        float4 a3 = *(const float4*)&A[(size_t)(i0 + sm) * IN_FT + k0 + sk + 12];
        float4 a4 = *(const float4*)&A[(size_t)(i0 + 64 + sm) * IN_FT + k0 + sk + 0];
        float4 a5 = *(const float4*)&A[(size_t)(i0 + 64 + sm) * IN_FT + k0 + sk + 4];
        float4 a6 = *(const float4*)&A[(size_t)(i0 + 64 + sm) * IN_FT + k0 + sk + 8];
        float4 a7 = *(const float4*)&A[(size_t)(i0 + 64 + sm) * IN_FT + k0 + sk + 12];
        float4 b0 = *(const float4*)&A[(size_t)(j0 + sm) * IN_FT + k0 + sk + 0];
        float4 b1 = *(const float4*)&A[(size_t)(j0 + sm) * IN_FT + k0 + sk + 4];
        float4 b2 = *(const float4*)&A[(size_t)(j0 + sm) * IN_FT + k0 + sk + 8];
        float4 b3 = *(const float4*)&A[(size_t)(j0 + sm) * IN_FT + k0 + sk + 12];
        float4 b4 = *(const float4*)&A[(size_t)(j0 + 64 + sm) * IN_FT + k0 + sk + 0];
        float4 b5 = *(const float4*)&A[(size_t)(j0 + 64 + sm) * IN_FT + k0 + sk + 4];
        float4 b6 = *(const float4*)&A[(size_t)(j0 + 64 + sm) * IN_FT + k0 + sk + 8];
        float4 b7 = *(const float4*)&A[(size_t)(j0 + 64 + sm) * IN_FT + k0 + sk + 12];
        __syncthreads();                      // previous iter's LDS reads done
        As[sk + 0][sm] = a0.x;       As[sk + 1][sm] = a0.y;
        As[sk + 2][sm] = a0.z;       As[sk + 3][sm] = a0.w;
        As[sk + 4][sm] = a1.x;       As[sk + 5][sm] = a1.y;
        As[sk + 6][sm] = a1.z;       As[sk + 7][sm] = a1.w;
        As[sk + 8][sm] = a2.x;       As[sk + 9][sm] = a2.y;
        As[sk + 10][sm] = a2.z;      As[sk + 11][sm] = a2.w;
        As[sk + 12][sm] = a3.x;      As[sk + 13][sm] = a3.y;
        As[sk + 14][sm] = a3.z;      As[sk + 15][sm] = a3.w;
        As[sk + 0][64 + sm] = a4.x;  As[sk + 1][64 + sm] = a4.y;
        As[sk + 2][64 + sm] = a4.z;  As[sk + 3][64 + sm] = a4.w;
        As[sk + 4][64 + sm] = a5.x;  As[sk + 5][64 + sm] = a5.y;
        As[sk + 6][64 + sm] = a5.z;  As[sk + 7][64 + sm] = a5.w;
        As[sk + 8][64 + sm] = a6.x;  As[sk + 9][64 + sm] = a6.y;
        As[sk + 10][64 + sm] = a6.z; As[sk + 11][64 + sm] = a6.w;
        As[sk + 12][64 + sm] = a7.x; As[sk + 13][64 + sm] = a7.y;
        As[sk + 14][64 + sm] = a7.z; As[sk + 15][64 + sm] = a7.w;
        Bs[sk + 0][pb0] = b0.x;  Bs[sk + 1][pb0] = b0.y;
        Bs[sk + 2][pb0] = b0.z;  Bs[sk + 3][pb0] = b0.w;
        Bs[sk + 4][pb0] = b1.x;  Bs[sk + 5][pb0] = b1.y;
        Bs[sk + 6][pb0] = b1.z;  Bs[sk + 7][pb0] = b1.w;
        Bs[sk + 8][pb0] = b2.x;  Bs[sk + 9][pb0] = b2.y;
        Bs[sk + 10][pb0] = b2.z; Bs[sk + 11][pb0] = b2.w;
        Bs[sk + 12][pb0] = b3.x; Bs[sk + 13][pb0] = b3.y;
        Bs[sk + 14][pb0] = b3.z; Bs[sk + 15][pb0] = b3.w;
        Bs[sk + 0][pb1] = b4.x;  Bs[sk + 1][pb1] = b4.y;
        Bs[sk + 2][pb1] = b4.z;  Bs[sk + 3][pb1] = b4.w;
        Bs[sk + 4][pb1] = b5.x;  Bs[sk + 5][pb1] = b5.y;
        Bs[sk + 6][pb1] = b5.z;  Bs[sk + 7][pb1] = b5.w;
        Bs[sk + 8][pb1] = b6.x;  Bs[sk + 9][pb1] = b6.y;
        Bs[sk + 10][pb1] = b6.z; Bs[sk + 11][pb1] = b6.w;
        Bs[sk + 12][pb1] = b7.x; Bs[sk + 13][pb1] = b7.y;
        Bs[sk + 14][pb1] = b7.z; Bs[sk + 15][pb1] = b7.w;
        __syncthreads();
#pragma unroll
        for (int k = 0; k < CK; ++k) {
            // A logical rows ty*16..+15 = phys floats 16*ty..+15 (identity)
            float4 af0 = *(const float4*)&As[k][16 * ty + 0];
            float4 af1 = *(const float4*)&As[k][16 * ty + 4];
            float4 af2 = *(const float4*)&As[k][16 * ty + 8];
            float4 af3 = *(const float4*)&As[k][16 * ty + 12];
            // B logical cols tx*8..+7 = phys float4s tx and 16+tx (chunk perm)
            float4 bg0 = *(const float4*)&Bs[k][4 * tx];
            float4 bg1 = *(const float4*)&Bs[k][64 + 4 * tx];
            float a[16] = {af0.x, af0.y, af0.z, af0.w, af1.x, af1.y, af1.z, af1.w,
                           af2.x, af2.y, af2.z, af2.w, af3.x, af3.y, af3.z, af3.w};
            float b[8] = {bg0.x, bg0.y, bg0.z, bg0.w, bg1.x, bg1.y, bg1.z, bg1.w};
#pragma unroll
            for (int i = 0; i < 16; ++i)
#pragma unroll
                for (int j = 0; j < 8; ++j) acc[i][j] += a[i] * b[j];
        }
    }
    // upper block store (row-contiguous float4)
#pragma unroll
    for (int i = 0; i < 16; ++i) {
        int r = i0 + ty * 16 + i;
        float4 s0 = make_float4(acc[i][0], acc[i][1], acc[i][2], acc[i][3]);
        float4 s1 = make_float4(acc[i][4], acc[i][5], acc[i][6], acc[i][7]);
        *(float4*)&C[(size_t)r * N + j0 + tx * 8 + 0] = s0;
        *(float4*)&C[(size_t)r * N + j0 + tx * 8 + 4] = s1;
    }
    // mirrored block store (bit-identical values: IEEE a*b == b*a)
    if (bx != by) {
#pragma unroll
        for (int j = 0; j < 8; ++j) {
            int r = j0 + tx * 8 + j;
#pragma unroll
            for (int g = 0; g < 4; ++g) {
                float4 s = make_float4(acc[g * 4 + 0][j], acc[g * 4 + 1][j],
                                       acc[g * 4 + 2][j], acc[g * 4 + 3][j]);
                *(float4*)&C[(size_t)r * N + i0 + ty * 16 + g * 4] = s;
            }
        }
    }
}

// ---------- per-row top-k + threshold -> transposed bitmask + row sparse list ----------
__global__ __launch_bounds__(256) void topk_mask_k(const float* __restrict__ cosm,
                                                   unsigned* __restrict__ maskT,
                                                   const float* __restrict__ w2,
                                                   const float* __restrict__ Hmat,
                                                   int* __restrict__ rlist,
                                                   float* __restrict__ rval,
                                                   int* __restrict__ rcnt) {
    int row = blockIdx.x;
    int tid = threadIdx.x;
    __shared__ unsigned char flag[N];
    __shared__ float wbv[4];
    __shared__ int wbi[4];
    __shared__ int wcnt[4];
    __shared__ int basev;
    int lane = tid & 63, wid = tid >> 6;
    const float* crow = cosm + (size_t)row * N;
    float v[16];
    unsigned fl = 0;
#pragma unroll
    for (int q = 0; q < 4; ++q) {
        float4 f4 = *(const float4*)&crow[tid * 16 + q * 4];
        v[q * 4 + 0] = f4.x; v[q * 4 + 1] = f4.y;
        v[q * 4 + 2] = f4.z; v[q * 4 + 3] = f4.w;
    }
#pragma unroll
    for (int c = 0; c < 16; ++c)
        if (v[c] > COS_THR) fl |= 1u << c;
    for (int t = 0; t < COS_K; ++t) {
        float best = -INFINITY;
        int bidx = 0x7fffffff;
#pragma unroll
        for (int c = 0; c < 16; ++c)
            if (v[c] > best) { best = v[c]; bidx = tid * 16 + c; }
#pragma unroll
        for (int off = 32; off > 0; off >>= 1) {
            float v2 = __shfl_xor(best, off);
            int i2 = __shfl_xor(bidx, off);
            if (v2 > best || (v2 == best && i2 < bidx)) { best = v2; bidx = i2; }
        }
        __syncthreads();
        if (lane == 0) { wbv[wid] = best; wbi[wid] = bidx; }
        __syncthreads();
        float fb = wbv[0]; int fi = wbi[0];
#pragma unroll
        for (int w = 1; w < 4; ++w) {
            float v2 = wbv[w]; int i2 = wbi[w];
            if (v2 > fb || (v2 == fb && i2 < fi)) { fb = v2; fi = i2; }
        }
        if ((fi >> 4) == tid) {                // owning thread invalidates + flags
            v[fi & 15] = -INFINITY;
            fl |= 1u << (fi & 15);
        }
    }
#pragma unroll
    for (int c = 0; c < 16; ++c) flag[tid * 16 + c] = (fl >> c) & 1;
    __syncthreads();
    for (int wdx = tid; wdx < NW; wdx += 256) {
        unsigned bits = 0;
#pragma unroll
        for (int b = 0; b < 32; ++b) bits |= (flag[wdx * 32 + b] ? 1u : 0u) << b;
        maskT[(size_t)wdx * N + row] = bits;
    }
    if (tid == 0) basev = 0;
    __syncthreads();
    for (int c = 0; c < 16; ++c) {
        int j = c * 256 + tid;
        bool f = flag[j] != 0;
        unsigned long long b = __ballot(f);
        if (lane == 0) wcnt[wid] = __popcll(b);
        __syncthreads();
        int off = basev;
        for (int w = 0; w < wid; ++w) off += wcnt[w];
        int pos = off + __popcll(b & ((1ull << lane) - 1ull));
        if (f && pos < CAP) {
            size_t ofs = (size_t)row * N + j;
            rlist[(size_t)row * CAP + pos] = j;
            rval[(size_t)row * CAP + pos] = w2[ofs] * Hmat[ofs];
        }
        __syncthreads();
        if (tid == 0) basev += wcnt[0] + wcnt[1] + wcnt[2] + wcnt[3];
        __syncthreads();
    }
    if (tid == 0) rcnt[row] = basev < CAP ? basev : CAP;
}

// ---------- split x and proj_w into bf16 (hi, lo) pairs ----------
__global__ __launch_bounds__(256) void cast_split_k(const float* __restrict__ x,
                                                    const float* __restrict__ w,
                                                    unsigned short* __restrict__ xh,
                                                    unsigned short* __restrict__ xl,
                                                    unsigned short* __restrict__ wh,
                                                    unsigned short* __restrict__ wl) {
    const int totx = (N * IN_FT) / 4;          // 524288 float4s
    int idx = blockIdx.x * 256 + threadIdx.x;  // grid sized exactly
    bool isx = idx < totx;
    int i4 = isx ? idx : idx - totx;
    float4 f = isx ? ((const float4*)x)[i4] : ((const float4*)w)[i4];
    ushort4 hi, lo;
    hi.x = f2bf(f.x); lo.x = f2bf(f.x - bf2f(hi.x));
    hi.y = f2bf(f.y); lo.y = f2bf(f.y - bf2f(hi.y));
    hi.z = f2bf(f.z); lo.z = f2bf(f.z - bf2f(hi.z));
    hi.w = f2bf(f.w); lo.w = f2bf(f.w - bf2f(hi.w));
    if (isx) { ((ushort4*)xh)[i4] = hi; ((ushort4*)xl)[i4] = lo; }
    else     { ((ushort4*)wh)[i4] = hi; ((ushort4*)wl)[i4] = lo; }
}

// ---------- h = x @ proj_w^T + b via bf16x3 MFMA (err ~1e-5; not a selection path) ----------
__global__ __launch_bounds__(256) void proj_mfma_k(const unsigned short* __restrict__ xh,
                                                   const unsigned short* __restrict__ xl,
                                                   const unsigned short* __restrict__ wh,
                                                   const unsigned short* __restrict__ wl,
                                                   const float* __restrict__ bias,
                                                   float* __restrict__ h) {
    int tid = threadIdx.x;
    int wave = tid >> 6, l = tid & 63;
    int m0 = blockIdx.y * 64 + wave * 16;
    int n0 = blockIdx.x * 64;
    int lr = l & 15;
    int kq = (l >> 4) * 8;
    const unsigned short* pah = xh + (size_t)(m0 + lr) * IN_FT + kq;
    const unsigned short* pal = xl + (size_t)(m0 + lr) * IN_FT + kq;
    f32x4 acc[4] = {};
    for (int k0 = 0; k0 < IN_FT; k0 += 32) {
        s16x8 ah = *(const s16x8*)(pah + k0);
        s16x8 al = *(const s16x8*)(pal + k0);
#pragma unroll
        for (int g = 0; g < 4; ++g) {
            const unsigned short* pbh = wh + (size_t)(n0 + g * 16 + lr) * IN_FT + kq + k0;
            const unsigned short* pbl = wl + (size_t)(n0 + g * 16 + lr) * IN_FT + kq + k0;
            s16x8 bh = *(const s16x8*)pbh;
            s16x8 bl = *(const s16x8*)pbl;
            acc[g] = __builtin_amdgcn_mfma_f32_16x16x32_bf16(ah, bh, acc[g], 0, 0, 0);
            acc[g] = __builtin_amdgcn_mfma_f32_16x16x32_bf16(ah, bl, acc[g], 0, 0, 0);
            acc[g] = __builtin_amdgcn_mfma_f32_16x16x32_bf16(al, bh, acc[g], 0, 0, 0);
        }
    }
#pragma unroll
    for (int g = 0; g < 4; ++g) {
#pragma unroll
        for (int r = 0; r < 4; ++r) {
            int m = m0 + (l >> 4) * 4 + r;
            int n = n0 + g * 16 + lr;
            h[(size_t)m * OUT_FT + n] = acc[g][r] + bias[n];
        }
    }
}

// ---------- column build pass 1: per-(v-chunk, e) bit counts ----------
__global__ __launch_bounds__(256) void count_cols_k(const unsigned* __restrict__ maskT,
                                                    int* __restrict__ cnt16) {
    __shared__ unsigned ch[8][256];
    int tid = threadIdx.x;
    int eb = blockIdx.x, chunk = blockIdx.y;
    int wbase = eb * 8, v0 = chunk * 256;
#pragma unroll
    for (int i = 0; i < 8; ++i)
        ch[i][tid] = maskT[(size_t)(wbase + i) * N + v0 + tid];
    __syncthreads();
    int wl = tid >> 5, bp = tid & 31;
    int cnt = 0;
#pragma unroll 8
    for (int v = 0; v < 256; ++v) cnt += (ch[wl][v] >> bp) & 1;
    cnt16[chunk * N + eb * 256 + tid] = cnt;
}

// ---------- column build pass 2: fill at prefix offsets (deterministic) ----------
__global__ __launch_bounds__(256) void fill_cols_k(const unsigned* __restrict__ maskT,
                                                   const int* __restrict__ cnt16,
                                                   const float* __restrict__ w1,
                                                   const float* __restrict__ Hmat,
                                                   int* __restrict__ elist,
                                                   float* __restrict__ eval_,
                                                   int* __restrict__ ecnt) {
    __shared__ unsigned ch[8][256];
    int tid = threadIdx.x;
    int eb = blockIdx.x, chunk = blockIdx.y;
    int e = eb * 256 + tid;
    int wbase = eb * 8, v0 = chunk * 256;
#pragma unroll
    for (int i = 0; i < 8; ++i)
        ch[i][tid] = maskT[(size_t)(wbase + i) * N + v0 + tid];
    int pos = 0;
    for (int c = 0; c < chunk; ++c) pos += cnt16[c * N + e];
    __syncthreads();
    int wl = tid >> 5;
    unsigned bit = 1u << (tid & 31);
    for (int v = 0; v < 256; ++v) {
        if (ch[wl][v] & bit) {
            if (pos < CAP) {
                size_t ofs = (size_t)(v0 + v) * N + e;
                elist[(size_t)e * CAP + pos] = v0 + v;
                eval_[(size_t)e * CAP + pos] = w1[ofs] * Hmat[ofs];
            }
            ++pos;
        }
    }
    if (chunk == 15) ecnt[e] = pos < CAP ? pos : CAP;
}

// ---------- dst[i,:] = (1/max(sum|val|,eps)) * sum val*src[list,:] ----------
__global__ __launch_bounds__(256) void spmm_k(const int* __restrict__ list,
                                              const float* __restrict__ val,
                                              const int* __restrict__ cnt,
                                              const float* __restrict__ src,
                                              float* __restrict__ dst) {
    int i = blockIdx.x;
    int f2 = threadIdx.x;                      // float2 index 0..255
    int c = cnt[i];
    float ssum = 0.f;
    for (int t = 0; t < c; ++t) ssum += fabsf(val[(size_t)i * CAP + t]);
    float acc0 = 0.f, acc1 = 0.f;
    for (int t = 0; t < c; ++t) {
        int j = list[(size_t)i * CAP + t];
        float a = val[(size_t)i * CAP + t];
        float2 s = *(const float2*)&src[(size_t)j * OUT_FT + f2 * 2];
        acc0 += a * s.x;
        acc1 += a * s.y;
    }
    float sc = 1.0f / fmaxf(ssum, EPSN);
    float2 o = make_float2(acc0 * sc, acc1 * sc);
    *(float2*)&dst[(size_t)i * OUT_FT + f2 * 2] = o;
}

extern "C" void kernel_launch(void* const* d_in, const int* in_sizes, int n_in,
                              void* d_out, int out_size, void* d_ws, size_t ws_size,
                              hipStream_t stream) {
    const float* x      = (const float*)d_in[0];   // [4096,512]
    const float* Hmat   = (const float*)d_in[1];   // [4096,4096]
    const float* proj_w = (const float*)d_in[2];   // [512,512]
    const float* proj_b = (const float*)d_in[3];   // [512]
    const float* w1     = (const float*)d_in[4];   // [4096,4096]
    const float* w2     = (const float*)d_in[5];   // [4096,4096]
    float* out = (float*)d_out;

    char* ws = (char*)d_ws;
    float*          xn    = (float*)(ws + 0);           //  8 MB
    float*          cosm  = (float*)(ws + 8388608);     // 64 MB [8MB..72MB), dead after topk
    int*            elist = (int*)  (ws + 8388608);     //  4 MB (aliases dead cos)
    float*          eval_ = (float*)(ws + 12582912);    //  4 MB (aliases dead cos)
    float*          h     = (float*)(ws + 25165824);    //  8 MB (aliases dead cos)
    float*          h2    = (float*)(ws + 33554432);    //  8 MB (aliases dead cos)
    unsigned short* xhi   = (unsigned short*)(ws + 41943040);  // 4 MB (aliases dead cos)
    unsigned short* xlo   = (unsigned short*)(ws + 46137344);  // 4 MB (aliases dead cos)
    unsigned short* whi   = (unsigned short*)(ws + 50331648);  // 512 KB (aliases dead cos)
    unsigned short* wlo   = (unsigned short*)(ws + 50855936);  // 512 KB (aliases dead cos)
    unsigned*       maskT = (unsigned*)(ws + 75497472); //  2 MB (outside cos)
    int*            ecnt  = (int*)  (ws + 77594624);    // 16 KB
    int*            rcnt  = (int*)  (ws + 77611008);    // 16 KB
    int*            rlist = (int*)  (ws + 77660160);    //  4 MB (outside cos)
    float*          rval  = (float*)(ws + 81854464);    //  4 MB (outside cos)
    int*            cnt16 = (int*)  (ws + 86048768);    // 256 KB [16][4096]

    // 1. xn = x / max(||x||, eps)
    rownorm_k<<<N, 256, 0, stream>>>(x, xn);
    // 2. cos = xn @ xn^T: upper-tri blocks, mirror fused (bit-identical values)
    cos_sym_k<<<CNB * (CNB + 1) / 2, 128, 0, stream>>>(xn, cosm);
    // 3. topk/threshold -> maskT + row sparse lists (selection-identical)
    topk_mask_k<<<N, 256, 0, stream>>>(cosm, maskT, w2, Hmat, rlist, rval, rcnt);
    // 4. h = x @ proj_w^T + proj_b  (bf16x3 MFMA; buffers alias dead cos)
    cast_split_k<<<(N * IN_FT + OUT_FT * IN_FT) / 1024, 256, 0, stream>>>(
        x, proj_w, xhi, xlo, whi, wlo);
    proj_mfma_k<<<dim3(OUT_FT / 64, N / 64), 256, 0, stream>>>(xhi, xlo, whi, wlo, proj_b, h);
    // 5. column lists: count -> fill at prefix offsets
    count_cols_k<<<dim3(16, 16), 256, 0, stream>>>(maskT, cnt16);
    fill_cols_k<<<dim3(16, 16), 256, 0, stream>>>(maskT, cnt16, w1, Hmat, elist, eval_, ecnt);
    // 6. h2[e,:] = normalize . gather-sum over column lists
    spmm_k<<<N, 256, 0, stream>>>(elist, eval_, ecnt, h, h2);
    // 7. out[v,:] = normalize . gather-sum over row lists
    spmm_k<<<N, 256, 0, stream>>>(rlist, rval, rcnt, h2, out);
}